// Round 12
// baseline (273.611 us; speedup 1.0000x reference)
//
#include <hip/hip_runtime.h>
#include <hip/hip_bf16.h>
#include <math.h>

#define HID 32
#define PW 8      // u32 words per plane row (16 dims as bf16x2)
#define POOLW 192 // 6 layers * 32
#define CAP 3072  // max edges per 128-node bucket (avg ~2048)
#define NBMAX 800 // max buckets (n<=102400)
#define ECHUNK 4096

typedef __hip_bfloat16 bf16;

__device__ __forceinline__ float bf_lo(unsigned w) {
    union { unsigned u; float f; } c; c.u = w << 16; return c.f;
}
__device__ __forceinline__ float bf_hi(unsigned w) {
    union { unsigned u; float f; } c; c.u = w & 0xFFFF0000u; return c.f;
}
__device__ __forceinline__ unsigned pack2(float a, float b) {
    union { bf16 bb[2]; unsigned u; } pk;
    pk.bb[0] = __float2bfloat16(a);
    pk.bb[1] = __float2bfloat16(b);
    return pk.u;
}

// ---------- bucket-level histogram (LDS-aggregated) ----------
__global__ __launch_bounds__(256) void k_bcount(const int* __restrict__ dst,
                                                int* __restrict__ bcount, int E, int NB) {
    __shared__ int hist[NBMAX];
    int t = threadIdx.x;
    int e0 = blockIdx.x * ECHUNK;
    int e1 = min(e0 + ECHUNK, E);
    for (int k = t; k < NB; k += 256) hist[k] = 0;
    __syncthreads();
    for (int e = e0 + t; e < e1; e += 256) atomicAdd(&hist[dst[e] >> 7], 1);
    __syncthreads();
    for (int k = t; k < NB; k += 256) {
        int c = hist[k];
        if (c > 0) atomicAdd(&bcount[k], c);
    }
}

// ---------- single-block exclusive scan of bucket counts ----------
__global__ __launch_bounds__(256) void k_bscan(const int* __restrict__ bcount,
                                               int* __restrict__ bstart,
                                               int* __restrict__ bcur, int NB) {
    __shared__ int sh[256];
    int t = threadIdx.x;
    int base = t * 4;
    int v0 = (base + 0 < NB) ? bcount[base + 0] : 0;
    int v1 = (base + 1 < NB) ? bcount[base + 1] : 0;
    int v2 = (base + 2 < NB) ? bcount[base + 2] : 0;
    int v3 = (base + 3 < NB) ? bcount[base + 3] : 0;
    int s = v0 + v1 + v2 + v3;
    sh[t] = s;
    __syncthreads();
    for (int off = 1; off < 256; off <<= 1) {
        int xv = (t >= off) ? sh[t - off] : 0;
        __syncthreads();
        sh[t] += xv;
        __syncthreads();
    }
    int excl = sh[t] - s;
    int o0 = excl, o1 = excl + v0, o2 = excl + v0 + v1, o3 = excl + v0 + v1 + v2;
    if (base + 0 < NB) { bstart[base+0]=o0; bcur[base+0]=o0; }
    if (base + 1 < NB) { bstart[base+1]=o1; bcur[base+1]=o1; }
    if (base + 2 < NB) { bstart[base+2]=o2; bcur[base+2]=o2; }
    if (base + 3 < NB) { bstart[base+3]=o3; bcur[base+3]=o3; }
    if (t == 255) bstart[NB] = sh[255];
}

// ---------- phase 1: block-aggregated binning into bucket windows ----------
__global__ __launch_bounds__(256) void k_bin(const int* __restrict__ src,
                                             const int* __restrict__ dst,
                                             int* __restrict__ bcur,
                                             unsigned* __restrict__ tmp,
                                             int E, int NB) {
    __shared__ int hist[NBMAX];
    int t = threadIdx.x;
    int e0 = blockIdx.x * ECHUNK;
    int e1 = min(e0 + ECHUNK, E);
    for (int k = t; k < NB; k += 256) hist[k] = 0;
    __syncthreads();
    for (int e = e0 + t; e < e1; e += 256) atomicAdd(&hist[dst[e] >> 7], 1);
    __syncthreads();
    for (int k = t; k < NB; k += 256) {
        int c = hist[k];
        hist[k] = (c > 0) ? atomicAdd(&bcur[k], c) : 0;
    }
    __syncthreads();
    for (int e = e0 + t; e < e1; e += 256) {
        int s = src[e], d = dst[e];
        int p = atomicAdd(&hist[d >> 7], 1);
        tmp[p] = (unsigned)s | ((unsigned)(d & 127) << 17);
    }
}

// ---------- phase 2: per bucket — degrees, offs, dinv, xs, CSR order ----------
__global__ __launch_bounds__(256) void k_csrdeg(const unsigned* __restrict__ tmp,
                                                const int* __restrict__ bstart,
                                                const float* __restrict__ x,
                                                int* __restrict__ offs,
                                                float* __restrict__ dinv,
                                                float* __restrict__ xs,
                                                int* __restrict__ csr_src,
                                                int n, int E) {
    __shared__ int cnt[128];
    __shared__ int sc[128];
    __shared__ int cur[128];
    __shared__ int win[CAP];
    int b = blockIdx.x;
    int node0 = b << 7;
    int nn = min(128, n - node0);
    int t = threadIdx.x;
    int base = bstart[b];
    int count = bstart[b + 1] - base;

    if (t < 128) cnt[t] = 0;
    __syncthreads();
    for (int k = t; k < count; k += 256) atomicAdd(&cnt[tmp[base + k] >> 17], 1);
    __syncthreads();
    if (t < 128) sc[t] = (t < nn) ? cnt[t] : 0;
    __syncthreads();
    for (int off = 1; off < 128; off <<= 1) {
        int v = (t < 128 && t >= off) ? sc[t - off] : 0;
        __syncthreads();
        if (t < 128) sc[t] += v;
        __syncthreads();
    }
    if (t < nn) {
        int excl = sc[t] - cnt[t];
        offs[node0 + t] = base + excl;
        cur[t] = excl;
        float di = rsqrtf((float)(cnt[t] + 1));
        dinv[node0 + t] = di;
        xs[node0 + t] = di * x[node0 + t];
        if (node0 + t + 1 == n) offs[n] = E;
    }
    __syncthreads();
    if (count <= CAP) {
        for (int k = t; k < count; k += 256) {
            unsigned v = tmp[base + k];
            int p = atomicAdd(&cur[v >> 17], 1);
            win[p] = v & 0x1FFFF;
        }
        __syncthreads();
        for (int k = t; k < count; k += 256) csr_src[base + k] = win[k];
    } else {  // safety fallback
        for (int k = t; k < count; k += 256) {
            unsigned v = tmp[base + k];
            int p = atomicAdd(&cur[v >> 17], 1);
            csr_src[base + p] = v & 0x1FFFF;
        }
    }
}

// ---------- layer 0: scalar gather + transform + pool + T1 (writes planes) ----------
__global__ __launch_bounds__(256) void k_layer0(
        const float* __restrict__ xs, unsigned* __restrict__ To0,
        unsigned* __restrict__ To1,
        const int* __restrict__ offs, const int* __restrict__ csr_src,
        const float* __restrict__ dinv, const float* __restrict__ b1,
        const float* __restrict__ W1, const float* __restrict__ W2,
        const int* __restrict__ batch, float* __restrict__ pooled, int n) {
    __shared__ float hred[16][HID];
    __shared__ float wsh[HID * HID];
    __shared__ int gid[16];
    int t = threadIdx.x;
    int il = t >> 4, jp = t & 15;
    int node = blockIdx.x * 16 + il;
    bool valid = node < n;

    for (int k = t; k < HID * HID; k += 256) wsh[k] = W2[k];

    float a = 0.f, di = 0.f;
    if (valid) {
        int s0 = offs[node], s1 = offs[node + 1];
        for (int k = s0 + jp; k < s1; k += 16) a += xs[csr_src[k]];
    }
    for (int d = 1; d < 16; d <<= 1) a += __shfl_xor(a, d, 16);
    float lo = 0.f, hi = 0.f;
    if (valid) {
        di = dinv[node];
        float tot = di * (a + xs[node]);  // + self loop
        lo = fmaxf(tot * W1[2 * jp] + b1[2 * jp], 0.f);
        hi = fmaxf(tot * W1[2 * jp + 1] + b1[2 * jp + 1], 0.f);
    }
    hred[il][2 * jp] = lo;
    hred[il][2 * jp + 1] = hi;
    if (jp == 0) gid[il] = valid ? batch[node] : -1;
    __syncthreads();

    if (t < HID) {
        float run = 0.f;
        int g = gid[0];
#pragma unroll
        for (int nn = 0; nn < 16; ++nn) {
            int gn = gid[nn];
            if (gn != g) {
                if (g >= 0) atomicAdd(&pooled[g * POOLW + t], run);
                run = 0.f;
                g = gn;
            }
            run += hred[nn][t];
        }
        if (g >= 0) atomicAdd(&pooled[g * POOLW + t], run);
    }

    if (valid) {
        float al = 0.f, ah = 0.f;
#pragma unroll
        for (int k2 = 0; k2 < HID; ++k2) {
            float hh = hred[il][k2];
            al += hh * wsh[k2 * HID + 2 * jp];
            ah += hh * wsh[k2 * HID + 2 * jp + 1];
        }
        unsigned u = pack2(di * al, di * ah);
        if (jp < 8) To0[node * PW + jp] = u;
        else        To1[node * PW + (jp - 8)] = u;
    }
}

// ---------- pass A: gather plane0 (dims 0..15), bias/relu, store hA, pool ----------
// 32 nodes/block, 8 lanes/node, 2 dims per lane.
__global__ __launch_bounds__(256) void k_passA(
        const unsigned* __restrict__ P0, unsigned* __restrict__ HA,
        const int* __restrict__ offs, const int* __restrict__ csr_src,
        const float* __restrict__ dinv, const float* __restrict__ bias,
        const int* __restrict__ batch, float* __restrict__ pooled,
        int n, int layer) {
    __shared__ float hred[32][17];
    __shared__ int gid[32];
    int t = threadIdx.x;
    int il = t >> 3, jp = t & 7;
    int node = blockIdx.x * 32 + il;
    bool valid = node < n;

    float lo = 0.f, hi = 0.f;
    if (valid) {
        unsigned w = P0[node * PW + jp];  // self loop
        float l0 = bf_lo(w), h0 = bf_hi(w);
        float l1 = 0, h1 = 0, l2 = 0, h2 = 0, l3 = 0, h3 = 0;
        int s0 = offs[node], s1 = offs[node + 1];
        int deg = s1 - s0;
        int iA = (jp < deg) ? csr_src[s0 + jp] : n;
        int iB = (jp + 8 < deg) ? csr_src[s0 + 8 + jp] : n;
        int iC = (jp + 16 < deg) ? csr_src[s0 + 16 + jp] : n;
        int iD = (jp + 24 < deg) ? csr_src[s0 + 24 + jp] : n;
        float* lp[4] = {&l0, &l1, &l2, &l3};
        float* hp[4] = {&h0, &h1, &h2, &h3};
#pragma unroll
        for (int i = 0; i < 8; ++i) {
            unsigned wv = P0[__shfl(iA, i, 8) * PW + jp];
            *lp[i & 3] += bf_lo(wv); *hp[i & 3] += bf_hi(wv);
        }
        if (deg > 8) {
#pragma unroll
            for (int i = 0; i < 8; ++i) {
                unsigned wv = P0[__shfl(iB, i, 8) * PW + jp];
                *lp[i & 3] += bf_lo(wv); *hp[i & 3] += bf_hi(wv);
            }
        }
        if (deg > 16) {
#pragma unroll
            for (int i = 0; i < 8; ++i) {
                unsigned wv = P0[__shfl(iC, i, 8) * PW + jp];
                *lp[i & 3] += bf_lo(wv); *hp[i & 3] += bf_hi(wv);
            }
        }
        if (deg > 24) {
#pragma unroll
            for (int i = 0; i < 8; ++i) {
                unsigned wv = P0[__shfl(iD, i, 8) * PW + jp];
                *lp[i & 3] += bf_lo(wv); *hp[i & 3] += bf_hi(wv);
            }
        }
        for (int k = s0 + 32; k < s1; ++k) {  // rare tail
            unsigned wv = P0[csr_src[k] * PW + jp];
            l0 += bf_lo(wv); h0 += bf_hi(wv);
        }
        float di = dinv[node];
        float accl = (l0 + l1) + (l2 + l3);
        float acch = (h0 + h1) + (h2 + h3);
        lo = fmaxf(di * accl + bias[2 * jp], 0.f);
        hi = fmaxf(di * acch + bias[2 * jp + 1], 0.f);
        HA[node * PW + jp] = pack2(lo, hi);
    }
    hred[il][2 * jp] = lo;
    hred[il][2 * jp + 1] = hi;
    if (jp == 0) gid[il] = valid ? batch[node] : -1;
    __syncthreads();

    if (t < 16) {
        float run = 0.f;
        int g = gid[0];
#pragma unroll
        for (int q = 0; q < 32; ++q) {
            int gn = gid[q];
            if (gn != g) {
                if (g >= 0) atomicAdd(&pooled[g * POOLW + layer * HID + t], run);
                run = 0.f;
                g = gn;
            }
            run += hred[q][t];
        }
        if (g >= 0) atomicAdd(&pooled[g * POOLW + layer * HID + t], run);
    }
}

// ---------- pass B: gather plane1 (dims 16..31), pool, transform into Tout ----------
__global__ __launch_bounds__(256) void k_passB(
        const unsigned* __restrict__ P1, const unsigned* __restrict__ HA,
        unsigned* __restrict__ To0, unsigned* __restrict__ To1,
        const int* __restrict__ offs, const int* __restrict__ csr_src,
        const float* __restrict__ dinv, const float* __restrict__ bias,
        const float* __restrict__ Wnext, const int* __restrict__ batch,
        float* __restrict__ pooled, int n, int layer, int last) {
    __shared__ float hsh[32][HID + 1];
    __shared__ float wsh[HID * HID];
    __shared__ int gid[32];
    int t = threadIdx.x;
    int il = t >> 3, jp = t & 7;
    int node = blockIdx.x * 32 + il;
    bool valid = node < n;

    if (!last) {
        for (int k = t; k < HID * HID; k += 256) wsh[k] = Wnext[k];
    }

    float lo = 0.f, hi = 0.f, di = 0.f;
    if (valid) {
        unsigned w = P1[node * PW + jp];  // self loop
        float l0 = bf_lo(w), h0 = bf_hi(w);
        float l1 = 0, h1 = 0, l2 = 0, h2 = 0, l3 = 0, h3 = 0;
        int s0 = offs[node], s1 = offs[node + 1];
        int deg = s1 - s0;
        int iA = (jp < deg) ? csr_src[s0 + jp] : n;
        int iB = (jp + 8 < deg) ? csr_src[s0 + 8 + jp] : n;
        int iC = (jp + 16 < deg) ? csr_src[s0 + 16 + jp] : n;
        int iD = (jp + 24 < deg) ? csr_src[s0 + 24 + jp] : n;
        float* lp[4] = {&l0, &l1, &l2, &l3};
        float* hp[4] = {&h0, &h1, &h2, &h3};
#pragma unroll
        for (int i = 0; i < 8; ++i) {
            unsigned wv = P1[__shfl(iA, i, 8) * PW + jp];
            *lp[i & 3] += bf_lo(wv); *hp[i & 3] += bf_hi(wv);
        }
        if (deg > 8) {
#pragma unroll
            for (int i = 0; i < 8; ++i) {
                unsigned wv = P1[__shfl(iB, i, 8) * PW + jp];
                *lp[i & 3] += bf_lo(wv); *hp[i & 3] += bf_hi(wv);
            }
        }
        if (deg > 16) {
#pragma unroll
            for (int i = 0; i < 8; ++i) {
                unsigned wv = P1[__shfl(iC, i, 8) * PW + jp];
                *lp[i & 3] += bf_lo(wv); *hp[i & 3] += bf_hi(wv);
            }
        }
        if (deg > 24) {
#pragma unroll
            for (int i = 0; i < 8; ++i) {
                unsigned wv = P1[__shfl(iD, i, 8) * PW + jp];
                *lp[i & 3] += bf_lo(wv); *hp[i & 3] += bf_hi(wv);
            }
        }
        for (int k = s0 + 32; k < s1; ++k) {  // rare tail
            unsigned wv = P1[csr_src[k] * PW + jp];
            l0 += bf_lo(wv); h0 += bf_hi(wv);
        }
        di = dinv[node];
        float accl = (l0 + l1) + (l2 + l3);
        float acch = (h0 + h1) + (h2 + h3);
        lo = fmaxf(di * accl + bias[16 + 2 * jp], 0.f);
        hi = fmaxf(di * acch + bias[17 + 2 * jp], 0.f);
        // fill h row: dims 16..31 from this pass, dims 0..15 from HA
        unsigned ha = HA[node * PW + jp];
        hsh[il][2 * jp] = bf_lo(ha);
        hsh[il][2 * jp + 1] = bf_hi(ha);
        hsh[il][16 + 2 * jp] = lo;
        hsh[il][17 + 2 * jp] = hi;
    } else {
        hsh[il][2 * jp] = 0.f; hsh[il][2 * jp + 1] = 0.f;
        hsh[il][16 + 2 * jp] = 0.f; hsh[il][17 + 2 * jp] = 0.f;
    }
    if (jp == 0) gid[il] = valid ? batch[node] : -1;
    __syncthreads();

    if (t < 16) {
        float run = 0.f;
        int g = gid[0];
#pragma unroll
        for (int q = 0; q < 32; ++q) {
            int gn = gid[q];
            if (gn != g) {
                if (g >= 0) atomicAdd(&pooled[g * POOLW + layer * HID + 16 + t], run);
                run = 0.f;
                g = gn;
            }
            run += hsh[q][16 + t];
        }
        if (g >= 0) atomicAdd(&pooled[g * POOLW + layer * HID + 16 + t], run);
    }

    if (!last && valid) {
        float a0 = 0.f, a1 = 0.f, a2 = 0.f, a3 = 0.f;
#pragma unroll
        for (int k = 0; k < HID; ++k) {
            float hh = hsh[il][k];
            a0 += hh * wsh[k * HID + 2 * jp];
            a1 += hh * wsh[k * HID + 2 * jp + 1];
            a2 += hh * wsh[k * HID + 16 + 2 * jp];
            a3 += hh * wsh[k * HID + 17 + 2 * jp];
        }
        To0[node * PW + jp] = pack2(di * a0, di * a1);
        To1[node * PW + jp] = pack2(di * a2, di * a3);
    }
}

// ---------- head: fc1(192->128) + relu + fc2(128->2) + softmax ----------
__global__ __launch_bounds__(128) void k_mlp(const float* __restrict__ pooled,
                                             const float* __restrict__ fc1_w,
                                             const float* __restrict__ fc1_b,
                                             const float* __restrict__ fc2_w,
                                             const float* __restrict__ fc2_b,
                                             float* __restrict__ out, int G) {
    __shared__ float z[POOLW];
    __shared__ float w0s[2], w1s[2];
    int g = blockIdx.x;
    int t = threadIdx.x;
    for (int k = t; k < POOLW; k += 128) z[k] = pooled[g * POOLW + k];
    __syncthreads();
    float a = fc1_b[t];
    for (int k = 0; k < POOLW; ++k) a += z[k] * fc1_w[k * 128 + t];
    float z1 = fmaxf(a, 0.f);
    float p0 = z1 * fc2_w[t * 2 + 0];
    float p1 = z1 * fc2_w[t * 2 + 1];
    for (int off = 32; off >= 1; off >>= 1) {
        p0 += __shfl_down(p0, off, 64);
        p1 += __shfl_down(p1, off, 64);
    }
    if ((t & 63) == 0) { w0s[t >> 6] = p0; w1s[t >> 6] = p1; }
    __syncthreads();
    if (t == 0) {
        float o0 = w0s[0] + w0s[1] + fc2_b[0];
        float o1 = w1s[0] + w1s[1] + fc2_b[1];
        float m = fmaxf(o0, o1);
        float e0 = expf(o0 - m), e1 = expf(o1 - m);
        float s = e0 + e1;
        out[g * 2 + 0] = e0 / s;
        out[g * 2 + 1] = e1 / s;
    }
}

extern "C" void kernel_launch(void* const* d_in, const int* in_sizes, int n_in,
                              void* d_out, int out_size, void* d_ws, size_t ws_size,
                              hipStream_t stream) {
    const float* x     = (const float*)d_in[0];
    const int*   ei    = (const int*)d_in[1];
    const int*   batch = (const int*)d_in[2];
    const float* Ws[6] = {(const float*)d_in[3], (const float*)d_in[5],
                          (const float*)d_in[7], (const float*)d_in[9],
                          (const float*)d_in[11], (const float*)d_in[13]};
    const float* bs[6] = {(const float*)d_in[4], (const float*)d_in[6],
                          (const float*)d_in[8], (const float*)d_in[10],
                          (const float*)d_in[12], (const float*)d_in[14]};
    const float* fc1_w = (const float*)d_in[15];
    const float* fc1_b = (const float*)d_in[16];
    const float* fc2_w = (const float*)d_in[17];
    const float* fc2_b = (const float*)d_in[18];

    int n = in_sizes[0];       // 100000
    int E = in_sizes[1] / 2;   // 1600000
    int G = out_size / 2;      // 256
    const int* src = ei;
    const int* dst = ei + E;
    int NB = (n + 127) / 128;  // buckets (782)

    char* p = (char*)d_ws;
    auto alloc = [&](size_t bytes) -> void* {
        void* r = (void*)p;
        p += (bytes + 255) / 256 * 256;
        return r;
    };
    int*      bcount  = (int*)alloc((size_t)NB * 4);
    int*      bstart  = (int*)alloc((size_t)(NB + 1) * 4);
    int*      bcur    = (int*)alloc((size_t)NB * 4);
    int*      offs    = (int*)alloc((size_t)(n + 1) * 4);
    float*    dinv    = (float*)alloc((size_t)n * 4);
    float*    xs      = (float*)alloc((size_t)n * 4);
    unsigned* tmp     = (unsigned*)alloc((size_t)E * 4);
    int*      csr_src = (int*)alloc((size_t)(E + 64) * 4);  // padded for masked loads
    unsigned* Ta0     = (unsigned*)alloc((size_t)(n + 1) * PW * 4);  // row n = zero
    unsigned* Ta1     = (unsigned*)alloc((size_t)(n + 1) * PW * 4);
    unsigned* Tb0     = (unsigned*)alloc((size_t)(n + 1) * PW * 4);
    unsigned* Tb1     = (unsigned*)alloc((size_t)(n + 1) * PW * 4);
    unsigned* HA      = (unsigned*)alloc((size_t)n * PW * 4);
    float*    pooled  = (float*)alloc((size_t)G * POOLW * 4);

    hipMemsetAsync(bcount, 0, (size_t)NB * 4, stream);
    hipMemsetAsync(pooled, 0, (size_t)G * POOLW * 4, stream);
    hipMemsetAsync(Ta0 + (size_t)n * PW, 0, PW * 4, stream);
    hipMemsetAsync(Ta1 + (size_t)n * PW, 0, PW * 4, stream);
    hipMemsetAsync(Tb0 + (size_t)n * PW, 0, PW * 4, stream);
    hipMemsetAsync(Tb1 + (size_t)n * PW, 0, PW * 4, stream);

    int nbE = (E + ECHUNK - 1) / ECHUNK;
    k_bcount<<<nbE, 256, 0, stream>>>(dst, bcount, E, NB);
    k_bscan<<<1, 256, 0, stream>>>(bcount, bstart, bcur, NB);
    k_bin<<<nbE, 256, 0, stream>>>(src, dst, bcur, tmp, E, NB);
    k_csrdeg<<<NB, 256, 0, stream>>>(tmp, bstart, x, offs, dinv, xs, csr_src, n, E);

    int nblk16 = (n + 15) / 16;
    int nblk32 = (n + 31) / 32;
    // layer 0: scalar gather, writes T planes for layer 1 into Tb*, pools slot 0
    k_layer0<<<nblk16, 256, 0, stream>>>(xs, Tb0, Tb1, offs, csr_src, dinv, bs[0],
                                         Ws[0], Ws[1], batch, pooled, n);
    unsigned* Ti0 = Tb0; unsigned* Ti1 = Tb1;
    unsigned* To0 = Ta0; unsigned* To1 = Ta1;
    for (int l = 1; l < 6; ++l) {
        int last = (l == 5);
        k_passA<<<nblk32, 256, 0, stream>>>(Ti0, HA, offs, csr_src, dinv, bs[l],
                                            batch, pooled, n, l);
        k_passB<<<nblk32, 256, 0, stream>>>(Ti1, HA, To0, To1, offs, csr_src, dinv,
                                            bs[l], last ? nullptr : Ws[l + 1], batch,
                                            pooled, n, l, last);
        unsigned* t0 = Ti0; Ti0 = To0; To0 = t0;
        unsigned* t1 = Ti1; Ti1 = To1; To1 = t1;
    }
    k_mlp<<<G, 128, 0, stream>>>(pooled, fc1_w, fc1_b, fc2_w, fc2_b, (float*)d_out, G);
}

// Round 13
// 209.743 us; speedup vs baseline: 1.3045x; 1.3045x over previous
//
#include <hip/hip_runtime.h>
#include <hip/hip_bf16.h>
#include <math.h>

#define HID 32
#define HIDW 16   // u32 words per node row (bf16x2)
#define POOLW 192 // 6 layers * 32
#define CAP 3072  // max edges per 128-node bucket (avg ~2048)
#define NBMAX 800 // max buckets (n<=102400)
#define ECHUNK 8192

typedef __hip_bfloat16 bf16;

__device__ __forceinline__ float bf_lo(unsigned w) {
    union { unsigned u; float f; } c; c.u = w << 16; return c.f;
}
__device__ __forceinline__ float bf_hi(unsigned w) {
    union { unsigned u; float f; } c; c.u = w & 0xFFFF0000u; return c.f;
}

// ---------- bucket-level histogram (LDS-aggregated), int4-vectorized reads ----------
__global__ __launch_bounds__(256) void k_bcount(const int* __restrict__ dst,
                                                int* __restrict__ bcount, int E, int NB) {
    __shared__ int hist[NBMAX];
    int t = threadIdx.x;
    int e0 = blockIdx.x * ECHUNK;
    int e1 = min(e0 + ECHUNK, E);
    for (int k = t; k < NB; k += 256) hist[k] = 0;
    __syncthreads();
    int e = e0 + t * 4;
    for (; e + 3 < e1; e += 1024) {
        int4 d4 = *reinterpret_cast<const int4*>(&dst[e]);
        atomicAdd(&hist[d4.x >> 7], 1);
        atomicAdd(&hist[d4.y >> 7], 1);
        atomicAdd(&hist[d4.z >> 7], 1);
        atomicAdd(&hist[d4.w >> 7], 1);
    }
    for (; e < e1; ++e) atomicAdd(&hist[dst[e] >> 7], 1);
    __syncthreads();
    for (int k = t; k < NB; k += 256) {
        int c = hist[k];
        if (c > 0) atomicAdd(&bcount[k], c);
    }
}

// ---------- single-block exclusive scan of bucket counts ----------
__global__ __launch_bounds__(256) void k_bscan(const int* __restrict__ bcount,
                                               int* __restrict__ bstart,
                                               int* __restrict__ bcur, int NB) {
    __shared__ int sh[256];
    int t = threadIdx.x;
    int base = t * 4;
    int v0 = (base + 0 < NB) ? bcount[base + 0] : 0;
    int v1 = (base + 1 < NB) ? bcount[base + 1] : 0;
    int v2 = (base + 2 < NB) ? bcount[base + 2] : 0;
    int v3 = (base + 3 < NB) ? bcount[base + 3] : 0;
    int s = v0 + v1 + v2 + v3;
    sh[t] = s;
    __syncthreads();
    for (int off = 1; off < 256; off <<= 1) {
        int xv = (t >= off) ? sh[t - off] : 0;
        __syncthreads();
        sh[t] += xv;
        __syncthreads();
    }
    int excl = sh[t] - s;
    int o0 = excl, o1 = excl + v0, o2 = excl + v0 + v1, o3 = excl + v0 + v1 + v2;
    if (base + 0 < NB) { bstart[base+0]=o0; bcur[base+0]=o0; }
    if (base + 1 < NB) { bstart[base+1]=o1; bcur[base+1]=o1; }
    if (base + 2 < NB) { bstart[base+2]=o2; bcur[base+2]=o2; }
    if (base + 3 < NB) { bstart[base+3]=o3; bcur[base+3]=o3; }
    if (t == 255) bstart[NB] = sh[255];
}

// ---------- phase 1: block-aggregated binning into bucket windows ----------
__global__ __launch_bounds__(256) void k_bin(const int* __restrict__ src,
                                             const int* __restrict__ dst,
                                             int* __restrict__ bcur,
                                             unsigned* __restrict__ tmp,
                                             int E, int NB) {
    __shared__ int hist[NBMAX];
    int t = threadIdx.x;
    int e0 = blockIdx.x * ECHUNK;
    int e1 = min(e0 + ECHUNK, E);
    for (int k = t; k < NB; k += 256) hist[k] = 0;
    __syncthreads();
    for (int e = e0 + t; e < e1; e += 256) atomicAdd(&hist[dst[e] >> 7], 1);
    __syncthreads();
    for (int k = t; k < NB; k += 256) {
        int c = hist[k];
        hist[k] = (c > 0) ? atomicAdd(&bcur[k], c) : 0;
    }
    __syncthreads();
    for (int e = e0 + t; e < e1; e += 256) {
        int s = src[e], d = dst[e];
        int p = atomicAdd(&hist[d >> 7], 1);
        tmp[p] = (unsigned)s | ((unsigned)(d & 127) << 17);
    }
}

// ---------- phase 2: per bucket — degrees, offs, dinv, xs, CSR order ----------
__global__ __launch_bounds__(256) void k_csrdeg(const unsigned* __restrict__ tmp,
                                                const int* __restrict__ bstart,
                                                const float* __restrict__ x,
                                                int* __restrict__ offs,
                                                float* __restrict__ dinv,
                                                float* __restrict__ xs,
                                                int* __restrict__ csr_src,
                                                unsigned* __restrict__ Tz0,
                                                unsigned* __restrict__ Tz1,
                                                int n, int E) {
    __shared__ int cnt[128];
    __shared__ int sc[128];
    __shared__ int cur[128];
    __shared__ int win[CAP];
    int b = blockIdx.x;
    int node0 = b << 7;
    int nn = min(128, n - node0);
    int t = threadIdx.x;
    int base = bstart[b];
    int count = bstart[b + 1] - base;

    if (b == 0 && t < HIDW) { Tz0[t] = 0u; Tz1[t] = 0u; }  // zero row n of T buffers

    if (t < 128) cnt[t] = 0;
    __syncthreads();
    for (int k = t; k < count; k += 256) atomicAdd(&cnt[tmp[base + k] >> 17], 1);
    __syncthreads();
    if (t < 128) sc[t] = (t < nn) ? cnt[t] : 0;
    __syncthreads();
    for (int off = 1; off < 128; off <<= 1) {
        int v = (t < 128 && t >= off) ? sc[t - off] : 0;
        __syncthreads();
        if (t < 128) sc[t] += v;
        __syncthreads();
    }
    if (t < nn) {
        int excl = sc[t] - cnt[t];
        offs[node0 + t] = base + excl;
        cur[t] = excl;
        float di = rsqrtf((float)(cnt[t] + 1));
        dinv[node0 + t] = di;
        xs[node0 + t] = di * x[node0 + t];
        if (node0 + t + 1 == n) offs[n] = E;
    }
    __syncthreads();
    if (count <= CAP) {
        for (int k = t; k < count; k += 256) {
            unsigned v = tmp[base + k];
            int p = atomicAdd(&cur[v >> 17], 1);
            win[p] = v & 0x1FFFF;
        }
        __syncthreads();
        for (int k = t; k < count; k += 256) csr_src[base + k] = win[k];
    } else {  // safety fallback
        for (int k = t; k < count; k += 256) {
            unsigned v = tmp[base + k];
            int p = atomicAdd(&cur[v >> 17], 1);
            csr_src[base + p] = v & 0x1FFFF;
        }
    }
}

// ---------- layer 0: scalar gather (x is [n,1]) + transform + pool + T1 ----------
__global__ __launch_bounds__(256) void k_layer0(
        const float* __restrict__ xs, unsigned* __restrict__ Tout,
        const int* __restrict__ offs, const int* __restrict__ csr_src,
        const float* __restrict__ dinv, const float* __restrict__ b1,
        const float* __restrict__ W1, const float* __restrict__ W2,
        const int* __restrict__ batch, float* __restrict__ pooled, int n) {
    __shared__ float hred[16][HID];
    __shared__ float wsh[HID * HID];
    __shared__ int gid[16];
    int t = threadIdx.x;
    int il = t >> 4, jp = t & 15;
    int node = blockIdx.x * 16 + il;
    bool valid = node < n;

    for (int k = t; k < HID * HID; k += 256) wsh[k] = W2[k];

    float a = 0.f, di = 0.f;
    if (valid) {
        int s0 = offs[node], s1 = offs[node + 1];
        for (int k = s0 + jp; k < s1; k += 16) a += xs[csr_src[k]];
    }
    for (int d = 1; d < 16; d <<= 1) a += __shfl_xor(a, d, 16);
    float lo = 0.f, hi = 0.f;
    if (valid) {
        di = dinv[node];
        float tot = di * (a + xs[node]);  // + self loop
        lo = fmaxf(tot * W1[2 * jp] + b1[2 * jp], 0.f);
        hi = fmaxf(tot * W1[2 * jp + 1] + b1[2 * jp + 1], 0.f);
    }
    hred[il][2 * jp] = lo;
    hred[il][2 * jp + 1] = hi;
    if (jp == 0) gid[il] = valid ? batch[node] : -1;
    __syncthreads();

    if (t < HID) {
        float run = 0.f;
        int g = gid[0];
#pragma unroll
        for (int nn = 0; nn < 16; ++nn) {
            int gn = gid[nn];
            if (gn != g) {
                if (g >= 0) atomicAdd(&pooled[g * POOLW + t], run);
                run = 0.f;
                g = gn;
            }
            run += hred[nn][t];
        }
        if (g >= 0) atomicAdd(&pooled[g * POOLW + t], run);
    }

    if (valid) {
        float al = 0.f, ah = 0.f;
#pragma unroll
        for (int k2 = 0; k2 < HID; ++k2) {
            float hh = hred[il][k2];
            al += hh * wsh[k2 * HID + 2 * jp];
            ah += hh * wsh[k2 * HID + 2 * jp + 1];
        }
        union { bf16 b[2]; unsigned u; } pk;
        pk.b[0] = __float2bfloat16(di * al);
        pk.b[1] = __float2bfloat16(di * ah);
        Tout[node * HIDW + jp] = pk.u;
    }
}

// ---------- fused layer (1..5): preloaded-index gather + pool + next T ----------
// 16 nodes per 256-thread block; 16 lanes per node, 2 dims (bf16x2) per lane.
// 32 edge indices preloaded via 2 coalesced loads + shfl distribution.
__global__ __launch_bounds__(256) void k_layer(
        const unsigned* __restrict__ Tin, unsigned* __restrict__ Tout,
        const int* __restrict__ offs, const int* __restrict__ csr_src,
        const float* __restrict__ dinv, const float* __restrict__ bias,
        const float* __restrict__ Wnext, const int* __restrict__ batch,
        float* __restrict__ pooled, int n, int layer, int last) {
    __shared__ float hred[16][HID];
    __shared__ float wsh[HID * HID];
    __shared__ int gid[16];
    int t = threadIdx.x;
    int il = t >> 4, jp = t & 15;
    int node = blockIdx.x * 16 + il;
    bool valid = node < n;

    if (!last) {
        for (int k = t; k < HID * HID; k += 256) wsh[k] = Wnext[k];
    }

    float lo = 0.f, hi = 0.f, di = 0.f;
    if (valid) {
        di = dinv[node];
        unsigned w = Tin[node * HIDW + jp];  // self loop
        float l0 = bf_lo(w), h0 = bf_hi(w);
        float l1 = 0, h1 = 0, l2 = 0, h2 = 0, l3 = 0, h3 = 0;
        float l4 = 0, h4 = 0, l5 = 0, h5 = 0, l6 = 0, h6 = 0, l7 = 0, h7 = 0;
        int s0 = offs[node], s1 = offs[node + 1];
        int deg = s1 - s0;
        int iA = (jp < deg) ? csr_src[s0 + jp] : n;
        int iB = (jp + 16 < deg) ? csr_src[s0 + 16 + jp] : n;
        float* lp[8] = {&l0, &l1, &l2, &l3, &l4, &l5, &l6, &l7};
        float* hp[8] = {&h0, &h1, &h2, &h3, &h4, &h5, &h6, &h7};
#pragma unroll
        for (int i = 0; i < 16; ++i) {
            int idx = __shfl(iA, i, 16);
            unsigned wv = Tin[idx * HIDW + jp];
            *lp[i & 7] += bf_lo(wv);
            *hp[i & 7] += bf_hi(wv);
        }
        if (deg > 16) {  // group-uniform; exec-masked when off
#pragma unroll
            for (int i = 0; i < 16; ++i) {
                int idx = __shfl(iB, i, 16);
                unsigned wv = Tin[idx * HIDW + jp];
                *lp[i & 7] += bf_lo(wv);
                *hp[i & 7] += bf_hi(wv);
            }
        }
        for (int k = s0 + 32; k < s1; ++k) {  // rare tail (P(deg>32) ~ 1e-4)
            unsigned wv = Tin[csr_src[k] * HIDW + jp];
            l0 += bf_lo(wv); h0 += bf_hi(wv);
        }
        float accl = ((l0 + l1) + (l2 + l3)) + ((l4 + l5) + (l6 + l7));
        float acch = ((h0 + h1) + (h2 + h3)) + ((h4 + h5) + (h6 + h7));
        lo = fmaxf(di * accl + bias[2 * jp], 0.f);
        hi = fmaxf(di * acch + bias[2 * jp + 1], 0.f);
    }
    hred[il][2 * jp] = lo;
    hred[il][2 * jp + 1] = hi;
    if (jp == 0) gid[il] = valid ? batch[node] : -1;
    __syncthreads();

    // pooling: segmented reduce over the block's 16 (sorted-batch) nodes
    if (t < HID) {
        float run = 0.f;
        int g = gid[0];
#pragma unroll
        for (int nn = 0; nn < 16; ++nn) {
            int gn = gid[nn];
            if (gn != g) {
                if (g >= 0) atomicAdd(&pooled[g * POOLW + layer * HID + t], run);
                run = 0.f;
                g = gn;
            }
            run += hred[nn][t];
        }
        if (g >= 0) atomicAdd(&pooled[g * POOLW + layer * HID + t], run);
    }

    // next-layer transform (2 output dims per lane), packed bf16x2 store
    if (!last && valid) {
        float al = 0.f, ah = 0.f;
#pragma unroll
        for (int k2 = 0; k2 < HID; ++k2) {
            float hh = hred[il][k2];
            al += hh * wsh[k2 * HID + 2 * jp];
            ah += hh * wsh[k2 * HID + 2 * jp + 1];
        }
        union { bf16 b[2]; unsigned u; } pk;
        pk.b[0] = __float2bfloat16(di * al);
        pk.b[1] = __float2bfloat16(di * ah);
        Tout[node * HIDW + jp] = pk.u;
    }
}

// ---------- head: fc1(192->128) + relu + fc2(128->2) + softmax ----------
__global__ __launch_bounds__(128) void k_mlp(const float* __restrict__ pooled,
                                             const float* __restrict__ fc1_w,
                                             const float* __restrict__ fc1_b,
                                             const float* __restrict__ fc2_w,
                                             const float* __restrict__ fc2_b,
                                             float* __restrict__ out, int G) {
    __shared__ float z[POOLW];
    __shared__ float w0s[2], w1s[2];
    int g = blockIdx.x;
    int t = threadIdx.x;
    for (int k = t; k < POOLW; k += 128) z[k] = pooled[g * POOLW + k];
    __syncthreads();
    float a = fc1_b[t];
    for (int k = 0; k < POOLW; ++k) a += z[k] * fc1_w[k * 128 + t];
    float z1 = fmaxf(a, 0.f);
    float p0 = z1 * fc2_w[t * 2 + 0];
    float p1 = z1 * fc2_w[t * 2 + 1];
    for (int off = 32; off >= 1; off >>= 1) {
        p0 += __shfl_down(p0, off, 64);
        p1 += __shfl_down(p1, off, 64);
    }
    if ((t & 63) == 0) { w0s[t >> 6] = p0; w1s[t >> 6] = p1; }
    __syncthreads();
    if (t == 0) {
        float o0 = w0s[0] + w0s[1] + fc2_b[0];
        float o1 = w1s[0] + w1s[1] + fc2_b[1];
        float m = fmaxf(o0, o1);
        float e0 = expf(o0 - m), e1 = expf(o1 - m);
        float s = e0 + e1;
        out[g * 2 + 0] = e0 / s;
        out[g * 2 + 1] = e1 / s;
    }
}

extern "C" void kernel_launch(void* const* d_in, const int* in_sizes, int n_in,
                              void* d_out, int out_size, void* d_ws, size_t ws_size,
                              hipStream_t stream) {
    const float* x     = (const float*)d_in[0];
    const int*   ei    = (const int*)d_in[1];
    const int*   batch = (const int*)d_in[2];
    const float* Ws[6] = {(const float*)d_in[3], (const float*)d_in[5],
                          (const float*)d_in[7], (const float*)d_in[9],
                          (const float*)d_in[11], (const float*)d_in[13]};
    const float* bs[6] = {(const float*)d_in[4], (const float*)d_in[6],
                          (const float*)d_in[8], (const float*)d_in[10],
                          (const float*)d_in[12], (const float*)d_in[14]};
    const float* fc1_w = (const float*)d_in[15];
    const float* fc1_b = (const float*)d_in[16];
    const float* fc2_w = (const float*)d_in[17];
    const float* fc2_b = (const float*)d_in[18];

    int n = in_sizes[0];       // 100000
    int E = in_sizes[1] / 2;   // 1600000
    int G = out_size / 2;      // 256
    const int* src = ei;
    const int* dst = ei + E;
    int NB = (n + 127) / 128;  // buckets (782)

    char* p = (char*)d_ws;
    auto alloc = [&](size_t bytes) -> void* {
        void* r = (void*)p;
        p += (bytes + 255) / 256 * 256;
        return r;
    };
    int*      bcount  = (int*)alloc((size_t)NB * 4);
    int*      bstart  = (int*)alloc((size_t)(NB + 1) * 4);
    int*      bcur    = (int*)alloc((size_t)NB * 4);
    int*      offs    = (int*)alloc((size_t)(n + 1) * 4);
    float*    dinv    = (float*)alloc((size_t)n * 4);
    float*    xs      = (float*)alloc((size_t)n * 4);
    unsigned* tmp     = (unsigned*)alloc((size_t)E * 4);
    int*      csr_src = (int*)alloc((size_t)(E + 64) * 4);  // padded for masked loads
    unsigned* Ta      = (unsigned*)alloc((size_t)(n + 1) * HIDW * 4);  // row n = zero
    unsigned* Tb      = (unsigned*)alloc((size_t)(n + 1) * HIDW * 4);  // row n = zero
    float*    pooled  = (float*)alloc((size_t)G * POOLW * 4);

    hipMemsetAsync(bcount, 0, (size_t)NB * 4, stream);
    hipMemsetAsync(pooled, 0, (size_t)G * POOLW * 4, stream);

    int nbE = (E + ECHUNK - 1) / ECHUNK;
    k_bcount<<<nbE, 256, 0, stream>>>(dst, bcount, E, NB);
    k_bscan<<<1, 256, 0, stream>>>(bcount, bstart, bcur, NB);
    k_bin<<<nbE, 256, 0, stream>>>(src, dst, bcur, tmp, E, NB);
    k_csrdeg<<<NB, 256, 0, stream>>>(tmp, bstart, x, offs, dinv, xs, csr_src,
                                     Ta + (size_t)n * HIDW, Tb + (size_t)n * HIDW, n, E);

    int nblk16 = (n + 15) / 16;
    // layer 0: scalar gather, writes T for layer 1 into Tb, pools slot 0
    k_layer0<<<nblk16, 256, 0, stream>>>(xs, Tb, offs, csr_src, dinv, bs[0],
                                         Ws[0], Ws[1], batch, pooled, n);
    unsigned* Tin = Tb;
    unsigned* Tout = Ta;
    for (int l = 1; l < 6; ++l) {
        int last = (l == 5);
        k_layer<<<nblk16, 256, 0, stream>>>(Tin, Tout, offs, csr_src, dinv, bs[l],
                                            last ? nullptr : Ws[l + 1], batch,
                                            pooled, n, l, last);
        unsigned* t2 = Tin; Tin = Tout; Tout = t2;
    }
    k_mlp<<<G, 128, 0, stream>>>(pooled, fc1_w, fc1_b, fc2_w, fc2_b, (float*)d_out, G);
}